// Round 12
// baseline (26.076 us; speedup 1.0000x reference)
//
#include <hip/hip_runtime.h>

// x,y float32 (B=2, C=1, D=32, H=128, W=128).
// out = mean over [B,C,D,3,H,3,W,3] of |d_c - d_n|, d = x - y, zero-padded
// neighbors. Per voxel: sum |c - n| over all 27 zero-padded neighbors.
// Structure: memset(d_out,0,4) node + ONE worker kernel; each block
// atomicAdds its pre-scaled partial into d_out[0] (device-scope, coherence
// point -> safe across non-coherent XCD L2s; non-returning -> no stalls).
constexpr int Dd = 32, Hh = 128, Ww = 128, Bv = 2;
constexpr int NVOX = Bv * Dd * Hh * Ww;     // 1,048,576
constexpr int BLK  = 512;                   // 8 waves/block

constexpr int TD = 2, TH = 4;               // tile 2 x 4 x 128 (full W rows)
constexpr int ZT = Dd / TD;                 // 16
constexpr int YT = Hh / TH;                 // 32
constexpr int NBLK = Bv * ZT * YT;          // 1024 blocks = 4/CU = 32 waves/CU
constexpr int LSTR = 136;                   // floats/LDS row; k = w + 4
constexpr int RZ = TD + 2, RY = TH + 2;     // halo: z in [z0-1,z0+2], y in [y0-1,y0+4]
constexpr int NROWS = RZ * RY;              // 24
constexpr int NF2   = LSTR / 2;             // 68 float2 slots per row
constexpr int NITEM = NROWS * NF2;          // 1632

__global__ void __launch_bounds__(BLK, 8)
cdl_worker(const float* __restrict__ xg, const float* __restrict__ yg,
           float* __restrict__ out)
{
    __shared__ float lds[NROWS * LSTR];     // 13,056 B
    __shared__ float smem[BLK / 64];

    const int tid = threadIdx.x;
    // XCD-aware bijective swizzle (NBLK % 8 == 0)
    const int bid = (blockIdx.x & 7) * (NBLK / 8) + (blockIdx.x >> 3);

    int t = bid;
    const int yt  = t & (YT - 1); t >>= 5;
    const int zt  = t & (ZT - 1); t >>= 4;
    const int vol = t;
    const int z0 = zt * TD, y0 = yt * TH;
    const size_t vbase = (size_t)vol * Dd * Hh * Ww;

    // ---- stage d = x - y halo tile into LDS (zero outside volume / w-pad) ----
    // float2 granularity: slot s covers k = 2s, 2s+1  ->  w = 2s-4, 2s-3.
#pragma unroll
    for (int p = 0; p < 4; ++p) {
        const int idx = p * BLK + tid;
        if (idx < NITEM) {
            const int row  = idx / NF2;
            const int slot = idx - row * NF2;
            const int lzr  = row / RY;
            const int lyr  = row - lzr * RY;
            const int gz = z0 + lzr - 1;        // [z0-1, z0+2]
            const int gy = y0 + lyr - 1;        // [y0-1, y0+4]
            const int w  = 2 * slot - 4;        // even; float2 covers w, w+1
            float2 v = make_float2(0.f, 0.f);
            if ((unsigned)gz < (unsigned)Dd && (unsigned)gy < (unsigned)Hh &&
                (unsigned)w <= 126u) {
                const size_t g = vbase + ((size_t)gz * Hh + gy) * Ww + w;
                const float2 a = *(const float2*)(xg + g);
                const float2 b = *(const float2*)(yg + g);
                v = make_float2(a.x - b.x, a.y - b.y);
            }
            *(float2*)&lds[row * LSTR + 2 * slot] = v;
        }
    }
    __syncthreads();

    // ---- compute: wave -> one (z,y) row; lane j -> voxels w = 2j, 2j+1 ----
    const int j  = tid & 63;                    // w-pair index
    const int r  = tid >> 6;                    // 0..7 (wave id)
    const int lz = r >> 2;                      // 0..1
    const int ly = r & 3;                       // 0..3
    const int k0 = 2 * j + 4;

    const float2 c = *(const float2*)&lds[((lz + 1) * RY + (ly + 1)) * LSTR + k0];

    float s = 0.f;
#pragma unroll
    for (int dz = 0; dz < 3; ++dz) {
#pragma unroll
        for (int dy = 0; dy < 3; ++dy) {
            const float* rp = &lds[((lz + dz) * RY + (ly + dy)) * LSTR];
            const float2 M = *(const float2*)&rp[k0 - 2];   // M.y = w-1
            const float2 A = *(const float2*)&rp[k0];       // w, w+1
            const float2 Q = *(const float2*)&rp[k0 + 2];   // Q.x = w+2
            s += fabsf(c.x - M.y) + fabsf(c.x - A.x) + fabsf(c.x - A.y);
            s += fabsf(c.y - A.x) + fabsf(c.y - A.y) + fabsf(c.y - Q.x);
        }
    }

    // ---- block reduction, one pre-scaled atomicAdd per block ----
    const int lane = tid & 63;
    const int wid  = tid >> 6;
#pragma unroll
    for (int off = 32; off > 0; off >>= 1) s += __shfl_down(s, off, 64);
    if (lane == 0) smem[wid] = s;
    __syncthreads();
    if (tid == 0) {
        float tsum = 0.f;
#pragma unroll
        for (int w = 0; w < BLK / 64; ++w) tsum += smem[w];
        const float scaled = (float)((double)tsum / (27.0 * (double)NVOX));
        atomicAdd(out, scaled);                 // device-scope, fire-and-forget
    }
}

extern "C" void kernel_launch(void* const* d_in, const int* in_sizes, int n_in,
                              void* d_out, int out_size, void* d_ws, size_t ws_size,
                              hipStream_t stream) {
    const float* x = (const float*)d_in[0];
    const float* y = (const float*)d_in[1];
    float* out     = (float*)d_out;

    // zero the accumulator each call (graph-capturable async memset node)
    hipMemsetAsync(out, 0, sizeof(float), stream);
    cdl_worker<<<NBLK, BLK, 0, stream>>>(x, y, out);
}

// Round 13
// 12.460 us; speedup vs baseline: 2.0927x; 2.0927x over previous
//
#include <hip/hip_runtime.h>

// x,y float32 (B=2, C=1, D=32, H=128, W=128).
// out = mean over [B,C,D,3,H,3,W,3] of |d_c - d_n|, d = x - y, zero-padded.
// SINGLE kernel node. Finish protocol: packed {count:16 | fixed-point sum:48}
// u64 atomics -- detection and accumulation are ONE atomic word, so no
// cross-address ordering is needed (the flaw in R5/R7-R9). Hierarchical:
// 16 group words (64 blocks each) -> 1 global word. Epoch detection:
// count-field >= 0xAAAA means 0xAA-poisoned word (harness poisons ws once);
// our global/group-last resets words to 0 each call -> subsequent calls clean.
// Fixed-point (x 2^16) makes every sum exact -> bit-identical deterministic.
constexpr int Dd = 32, Hh = 128, Ww = 128, Bv = 2;
constexpr int NVOX = Bv * Dd * Hh * Ww;     // 1,048,576
constexpr int BLK  = 512;                   // 8 waves/block

constexpr int TD = 2, TH = 4;               // tile 2 x 4 x 128 (full W rows)
constexpr int ZT = Dd / TD;                 // 16
constexpr int YT = Hh / TH;                 // 32
constexpr int NBLK = Bv * ZT * YT;          // 1024 blocks = 4/CU = 32 waves/CU
constexpr int LSTR = 136;                   // floats/LDS row; k = w + 4
constexpr int RZ = TD + 2, RY = TH + 2;     // halo: z in [z0-1,z0+2], y in [y0-1,y0+4]
constexpr int NROWS = RZ * RY;              // 24
constexpr int NF2   = LSTR / 2;             // 68 float2 slots per row
constexpr int NITEM = NROWS * NF2;          // 1632

constexpr int GRP  = 64;                    // blocks per group
constexpr int NGRP = NBLK / GRP;            // 16 groups

constexpr unsigned long long SUM_MASK   = ((unsigned long long)1 << 48) - 1;
constexpr unsigned long long ONE_CNT    = (unsigned long long)1 << 48;
constexpr unsigned long long POISON_CNT = 0xAAAAULL;
constexpr unsigned long long POISON_SUM = 0xAAAAAAAAAAAAULL;

__global__ void __launch_bounds__(BLK, 8)
cdl_kernel(const float* __restrict__ xg, const float* __restrict__ yg,
           unsigned long long* __restrict__ acc, float* __restrict__ out)
{
    __shared__ float lds[NROWS * LSTR];     // 13,056 B
    __shared__ float smem[BLK / 64];

    const int tid = threadIdx.x;
    // XCD-aware bijective swizzle (NBLK % 8 == 0)
    const int bid = (blockIdx.x & 7) * (NBLK / 8) + (blockIdx.x >> 3);

    int t = bid;
    const int yt  = t & (YT - 1); t >>= 5;
    const int zt  = t & (ZT - 1); t >>= 4;
    const int vol = t;
    const int z0 = zt * TD, y0 = yt * TH;
    const size_t vbase = (size_t)vol * Dd * Hh * Ww;

    // ---- stage d = x - y halo tile into LDS (zero outside volume / w-pad) ----
#pragma unroll
    for (int p = 0; p < 4; ++p) {
        const int idx = p * BLK + tid;
        if (idx < NITEM) {
            const int row  = idx / NF2;
            const int slot = idx - row * NF2;
            const int lzr  = row / RY;
            const int lyr  = row - lzr * RY;
            const int gz = z0 + lzr - 1;        // [z0-1, z0+2]
            const int gy = y0 + lyr - 1;        // [y0-1, y0+4]
            const int w  = 2 * slot - 4;        // even; float2 covers w, w+1
            float2 v = make_float2(0.f, 0.f);
            if ((unsigned)gz < (unsigned)Dd && (unsigned)gy < (unsigned)Hh &&
                (unsigned)w <= 126u) {
                const size_t g = vbase + ((size_t)gz * Hh + gy) * Ww + w;
                const float2 a = *(const float2*)(xg + g);
                const float2 b = *(const float2*)(yg + g);
                v = make_float2(a.x - b.x, a.y - b.y);
            }
            *(float2*)&lds[row * LSTR + 2 * slot] = v;
        }
    }
    __syncthreads();

    // ---- compute: wave -> one (z,y) row; lane j -> voxels w = 2j, 2j+1 ----
    const int j  = tid & 63;                    // w-pair index
    const int r  = tid >> 6;                    // 0..7 (wave id)
    const int lz = r >> 2;                      // 0..1
    const int ly = r & 3;                       // 0..3
    const int k0 = 2 * j + 4;

    const float2 c = *(const float2*)&lds[((lz + 1) * RY + (ly + 1)) * LSTR + k0];

    float s = 0.f;
#pragma unroll
    for (int dz = 0; dz < 3; ++dz) {
#pragma unroll
        for (int dy = 0; dy < 3; ++dy) {
            const float* rp = &lds[((lz + dz) * RY + (ly + dy)) * LSTR];
            const float2 M = *(const float2*)&rp[k0 - 2];   // M.y = w-1
            const float2 A = *(const float2*)&rp[k0];       // w, w+1
            const float2 Q = *(const float2*)&rp[k0 + 2];   // Q.x = w+2
            s += fabsf(c.x - M.y) + fabsf(c.x - A.x) + fabsf(c.x - A.y);
            s += fabsf(c.y - A.x) + fabsf(c.y - A.y) + fabsf(c.y - Q.x);
        }
    }

    // ---- block reduction ----
    const int lane = tid & 63;
    const int wid  = tid >> 6;
#pragma unroll
    for (int off = 32; off > 0; off >>= 1) s += __shfl_down(s, off, 64);
    if (lane == 0) smem[wid] = s;
    __syncthreads();

    // ---- packed-atomic hierarchical finish (tid 0 only) ----
    if (tid == 0) {
        float tsum = 0.f;
#pragma unroll
        for (int w = 0; w < BLK / 64; ++w) tsum += smem[w];
        // fixed-point, exact: q <= ~3e9 << 2^48
        const unsigned long long q =
            (unsigned long long)llrint((double)tsum * 65536.0);
        const int grp = bid >> 6;               // 0..15
        unsigned long long* gacc = &acc[32 * grp];        // 256B-separated lines

        const unsigned long long old = atomicAdd(gacc, ONE_CNT | q);
        const unsigned long long cnt = old >> 48;
        const bool pois  = cnt >= POISON_CNT;
        const unsigned long long cb  = pois ? POISON_CNT : 0ULL;
        if (cnt - cb == (unsigned long long)(GRP - 1)) {  // group-last
            const unsigned long long si = pois ? POISON_SUM : 0ULL;
            const unsigned long long gq = (old & SUM_MASK) + q - si;
            atomicExch(gacc, 0ULL);             // clean for next call
            unsigned long long* gl = &acc[32 * NGRP];
            const unsigned long long old2 = atomicAdd(gl, ONE_CNT | gq);
            const unsigned long long cnt2 = old2 >> 48;
            const bool p2 = cnt2 >= POISON_CNT;
            const unsigned long long cb2 = p2 ? POISON_CNT : 0ULL;
            if (cnt2 - cb2 == (unsigned long long)(NGRP - 1)) {  // global-last
                const unsigned long long s2 = p2 ? POISON_SUM : 0ULL;
                const unsigned long long tot = (old2 & SUM_MASK) + gq - s2;
                atomicExch(gl, 0ULL);
                out[0] = (float)((double)tot / 65536.0 / (27.0 * (double)NVOX));
            }
        }
    }
}

extern "C" void kernel_launch(void* const* d_in, const int* in_sizes, int n_in,
                              void* d_out, int out_size, void* d_ws, size_t ws_size,
                              hipStream_t stream) {
    const float* x = (const float*)d_in[0];
    const float* y = (const float*)d_in[1];
    unsigned long long* acc = (unsigned long long*)d_ws;
    float* out = (float*)d_out;

    cdl_kernel<<<NBLK, BLK, 0, stream>>>(x, y, acc, out);
}

// Round 14
// 11.233 us; speedup vs baseline: 2.3214x; 1.1093x over previous
//
#include <hip/hip_runtime.h>

// x,y float32 (B=2, C=1, D=32, H=128, W=128).
// out = mean over [B,C,D,3,H,3,W,3] of |d_c - d_n|, d = x - y, zero-padded.
// Pair-halved: T = 2*sp + corr,
//   sp   = sum_c sum_{o in 13 pos dirs} |d_c - pad(c+o)|   (zero-padded LDS)
//   corr = sum_c |d_c| * (n_minus(c) - n_plus(c)),
//   n_pm(c) = #{o in O : c -/+ o out of volume}, enumerated at compile time.
// Verified on 1D analog. Two-dispatch shell (proven in R6/R11).
constexpr int Dd = 32, Hh = 128, Ww = 128, Bv = 2;
constexpr int NVOX = Bv * Dd * Hh * Ww;     // 1,048,576
constexpr int BLK  = 512;                   // 8 waves/block
constexpr int BLKF = 256;

constexpr int TD = 2, TH = 4;               // tile 2 x 4 x 128 (full W rows)
constexpr int ZT = Dd / TD;                 // 16
constexpr int YT = Hh / TH;                 // 32
constexpr int NBLK = Bv * ZT * YT;          // 1024 blocks = 4/CU = 32 waves/CU
constexpr int LSTR = 136;                   // floats/LDS row; k = w + 4
constexpr int RZ = TD + 1, RY = TH + 2;     // halo: z in [z0, z0+TD], y in [y0-1, y0+TH]
constexpr int NROWS = RZ * RY;              // 18
constexpr int NF2   = LSTR / 2;             // 68 float2 slots per row
constexpr int NITEM = NROWS * NF2;          // 1224

// 13 positive directions (lexicographic half-space)
__device__ __constant__ const signed char DIRZ[13] = {1,1,1, 1,1,1, 1,1,1, 0,0,0, 0};
__device__ __constant__ const signed char DIRY[13] = {-1,-1,-1, 0,0,0, 1,1,1, 1,1,1, 0};
__device__ __constant__ const signed char DIRW[13] = {-1,0,1, -1,0,1, -1,0,1, -1,0,1, 1};

__global__ void __launch_bounds__(BLK, 8)
cdl_worker(const float* __restrict__ xg, const float* __restrict__ yg,
           float* __restrict__ partials)
{
    __shared__ float lds[NROWS * LSTR];     // 9,792 B
    __shared__ float smem[BLK / 64];

    const int tid = threadIdx.x;
    // XCD-aware bijective swizzle (NBLK % 8 == 0)
    const int bid = (blockIdx.x & 7) * (NBLK / 8) + (blockIdx.x >> 3);

    int t = bid;
    const int yt  = t & (YT - 1); t >>= 5;
    const int zt  = t & (ZT - 1); t >>= 4;
    const int vol = t;
    const int z0 = zt * TD, y0 = yt * TH;
    const size_t vbase = (size_t)vol * Dd * Hh * Ww;

    // ---- stage d = x - y halo tile into LDS (zero outside volume / w-pad) ----
    // rows: lzr in [0,TD] -> gz = z0+lzr ; lyr in [0,TH+1] -> gy = y0+lyr-1
#pragma unroll
    for (int p = 0; p < 3; ++p) {
        const int idx = p * BLK + tid;
        if (idx < NITEM) {
            const int row  = idx / NF2;
            const int slot = idx - row * NF2;
            const int lzr  = row / RY;
            const int lyr  = row - lzr * RY;
            const int gz = z0 + lzr;            // [z0, z0+TD]
            const int gy = y0 + lyr - 1;        // [y0-1, y0+TH]
            const int w  = 2 * slot - 4;        // even; float2 covers w, w+1
            float2 v = make_float2(0.f, 0.f);
            if ((unsigned)gz < (unsigned)Dd && (unsigned)gy < (unsigned)Hh &&
                (unsigned)w <= 126u) {
                const size_t g = vbase + ((size_t)gz * Hh + gy) * Ww + w;
                const float2 a = *(const float2*)(xg + g);
                const float2 b = *(const float2*)(yg + g);
                v = make_float2(a.x - b.x, a.y - b.y);
            }
            *(float2*)&lds[row * LSTR + 2 * slot] = v;
        }
    }
    __syncthreads();

    // ---- compute: wave -> one (z,y) row; lane j -> voxels w = 2j, 2j+1 ----
    const int j  = tid & 63;                    // w-pair index
    const int r  = tid >> 6;                    // 0..7 (wave id)
    const int lz = r >> 2;                      // 0..1 (local z)
    const int ly = r & 3;                       // 0..3 (local y)
    const int k0 = 2 * j + 4;

    // voxel row = (lz, ly+1)
    const float2 c = *(const float2*)&lds[(lz * RY + ly + 1) * LSTR + k0];

    float sp = 0.f;
    // dir (0,0,1): .x -> c.y (in register); .y -> own-row w+2
    {
        const float Qx = lds[(lz * RY + ly + 1) * LSTR + k0 + 2];
        sp += fabsf(c.x - c.y) + fabsf(c.y - Qx);
    }
    // dirs (0,1,dw) and (1,dy,dw): 4 full rows x 6 terms
#define ROW6(RP) do { const float* rp_ = (RP);                              \
        const float2 M = *(const float2*)&rp_[k0 - 2];                      \
        const float2 A = *(const float2*)&rp_[k0];                          \
        const float2 Q = *(const float2*)&rp_[k0 + 2];                      \
        sp += fabsf(c.x - M.y) + fabsf(c.x - A.x) + fabsf(c.x - A.y);       \
        sp += fabsf(c.y - A.x) + fabsf(c.y - A.y) + fabsf(c.y - Q.x);      \
    } while (0)
    ROW6(&lds[(lz * RY + ly + 2) * LSTR]);          // (z,   y+1)
    ROW6(&lds[((lz + 1) * RY + ly    ) * LSTR]);    // (z+1, y-1)
    ROW6(&lds[((lz + 1) * RY + ly + 1) * LSTR]);    // (z+1, y  )
    ROW6(&lds[((lz + 1) * RY + ly + 2) * LSTR]);    // (z+1, y+1)
#undef ROW6

    // ---- boundary correction: nd = n_minus - n_plus, enumerated dirs ----
    const int gz = z0 + lz, gy = y0 + ly;
    const bool zl = (gz == 0), zh = (gz == Dd - 1);
    const bool yl = (gy == 0), yh = (gy == Hh - 1);
    const bool wlx = (j == 0);                  // .x at w=2j:   w-1 OOB iff j==0
    const bool why = (j == 63);                 // .y at w=2j+1: w+1 OOB iff j==63
    int ndx = 0, ndy = 0;
#pragma unroll
    for (int q = 0; q < 13; ++q) {
        const int oz = DIRZ[q], oy = DIRY[q], ow = DIRW[q];
        // bad(s) = OOB(c + s) per component-sign flags
        // .x voxel: wl=wlx, wh=false ; .y voxel: wl=false, wh=why
        const bool bpx = (oz > 0 && zh) || (oy > 0 && yh) || (oy < 0 && yl)
                       || (ow < 0 && wlx);
        const bool bmx = (oz > 0 && zl) || (oy > 0 && yl) || (oy < 0 && yh)
                       || (ow > 0 && wlx);
        const bool bpy = (oz > 0 && zh) || (oy > 0 && yh) || (oy < 0 && yl)
                       || (ow > 0 && why);
        const bool bmy = (oz > 0 && zl) || (oy > 0 && yl) || (oy < 0 && yh)
                       || (ow < 0 && why);
        ndx += (int)bmx - (int)bpx;
        ndy += (int)bmy - (int)bpy;
    }

    float s = 2.f * sp + fabsf(c.x) * (float)ndx + fabsf(c.y) * (float)ndy;

    // ---- block reduction, plain-store publish ----
    const int lane = tid & 63;
    const int wid  = tid >> 6;
#pragma unroll
    for (int off = 32; off > 0; off >>= 1) s += __shfl_down(s, off, 64);
    if (lane == 0) smem[wid] = s;
    __syncthreads();
    if (tid == 0) {
        float tsum = 0.f;
#pragma unroll
        for (int w = 0; w < BLK / 64; ++w) tsum += smem[w];
        partials[bid] = tsum;
    }
}

__global__ void __launch_bounds__(BLKF)
cdl_finish(const float* __restrict__ partials, float* __restrict__ out)
{
    float acc = 0.f;
#pragma unroll
    for (int i = 0; i < NBLK / BLKF; ++i)
        acc += partials[i * BLKF + threadIdx.x];
#pragma unroll
    for (int off = 32; off > 0; off >>= 1) acc += __shfl_down(acc, off, 64);

    __shared__ float smem[BLKF / 64];
    const int lane = threadIdx.x & 63;
    const int wid  = threadIdx.x >> 6;
    if (lane == 0) smem[wid] = acc;
    __syncthreads();
    if (threadIdx.x == 0) {
        const double tot = (double)smem[0] + (double)smem[1] +
                           (double)smem[2] + (double)smem[3];
        out[0] = (float)(tot / (27.0 * (double)NVOX));
    }
}

extern "C" void kernel_launch(void* const* d_in, const int* in_sizes, int n_in,
                              void* d_out, int out_size, void* d_ws, size_t ws_size,
                              hipStream_t stream) {
    const float* x  = (const float*)d_in[0];
    const float* y  = (const float*)d_in[1];
    float* partials = (float*)d_ws;           // NBLK floats
    float* out      = (float*)d_out;

    cdl_worker<<<NBLK, BLK, 0, stream>>>(x, y, partials);
    cdl_finish<<<1, BLKF, 0, stream>>>(partials, out);
}